// Round 9
// baseline (307.087 us; speedup 1.0000x reference)
//
#include <hip/hip_runtime.h>
#include <math.h>

// Problem constants
#define D 512
#define NH 8
#define DK 64
#define S 2048
#define BATCH 4
#define N_TOK (BATCH * S)   // 8192

// fold 1/sqrt(dk) * log2(e) into Q so softmax numerator is exp2(q.k)
#define QSCALE 0.18033688f  // 0.125 * 1.4426950408889634

typedef __bf16 bf16x8 __attribute__((ext_vector_type(8)));
typedef __bf16 bf16x4 __attribute__((ext_vector_type(4)));
typedef float f32x4 __attribute__((ext_vector_type(4)));
typedef unsigned int u32x4 __attribute__((ext_vector_type(4)));

#define AS1 __attribute__((address_space(1)))
#define AS3 __attribute__((address_space(3)))

// Workspace layout (bytes):
//   [0,        8388608)   xb   bf16 (N_TOK, D)
//   [8388608, 10485760)   Wb   bf16 Wq|Wk|Wv|Wo stacked, (2048, 512)
//   [10485760,18874368)   Q    bf16 (b,h,s,dk)
//   [18874368,27262976)   K    bf16 (b,h,s,dk)
//   [27262976,35651584)   Vt   bf16 (b,h,dk,s) with keys PERMUTED within
//                              each 64-key chunk (see qkv V-store)
//   [35651584,44040192)   ctx  bf16 (tok, D)
//   [44040192,44040196)   flag int (1 = device buffers are fp32)
#define OFF_XB   0
#define OFF_WB   8388608
#define OFF_Q    10485760
#define OFF_K    18874368
#define OFF_VT   27262976
#define OFF_CTX  35651584
#define OFF_FLAG 44040192

static __device__ __forceinline__ bf16x8 ldg8(const __bf16* p) {
    return *(const bf16x8*)p;
}
static __device__ __forceinline__ f32x4 mfma16(bf16x8 a, bf16x8 b, f32x4 c) {
    return __builtin_amdgcn_mfma_f32_16x16x32_bf16(a, b, c, 0, 0, 0);
}
static __device__ __forceinline__ float ldf(const void* p, size_t i, int isf) {
    return isf ? ((const float*)p)[i] : (float)(((const __bf16*)p)[i]);
}
static __device__ __forceinline__ float fexp2(float x) {
#if __has_builtin(__builtin_amdgcn_exp2f)
    return __builtin_amdgcn_exp2f(x);   // bare v_exp_f32
#else
    return exp2f(x);
#endif
}
// pack hi16(e0) | hi16(e1)<<16  (bf16 truncation; folds to v_perm_b32)
static __device__ __forceinline__ unsigned pack_trunc(float e0, float e1) {
    return (__builtin_bit_cast(unsigned, e0) >> 16)
         | (__builtin_bit_cast(unsigned, e1) & 0xFFFF0000u);
}
// async global->LDS, 16B/lane; lds base wave-uniform, HW adds lane*16.
static __device__ __forceinline__ void gload_lds16(const void* g, void* l) {
    __builtin_amdgcn_global_load_lds((const AS1 char*)g, (AS3 char*)l, 16, 0, 0);
}

// ---------------------------------------------------------------------------
// Kernel 1: convert x and Wq|Wk|Wv|Wo to bf16 in ws. Self-detects dtype
// (wave-level probe of x interpreted as bf16: fp32 bit-soup gives |v|>64 or
// NaN with certainty over 512 samples); block 0 publishes flag downstream.
// ---------------------------------------------------------------------------
__global__ __launch_bounds__(256)
void cvt_kernel(const void* __restrict__ x,  const void* __restrict__ Wq,
                const void* __restrict__ Wk, const void* __restrict__ Wv,
                const void* __restrict__ Wo, __bf16* __restrict__ xb,
                __bf16* __restrict__ Wb, int* __restrict__ flag)
{
    // wave-uniform dtype probe
    const bf16x8 probe = ldg8((const __bf16*)x + (threadIdx.x & 63) * 8);
    int bad = 0;
#pragma unroll
    for (int j = 0; j < 8; ++j) bad |= !(fabsf((float)probe[j]) <= 64.0f);
    const int isf = __any(bad) ? 1 : 0;
    if (blockIdx.x == 0 && threadIdx.x == 0) *flag = isf;

    const size_t i0 = ((size_t)blockIdx.x * 256 + threadIdx.x) * 8;
    const void* src;
    __bf16* dst;
    size_t off;
    if (i0 < 4194304) {
        src = x; off = i0; dst = xb + i0;
    } else {
        const size_t wrel = i0 - 4194304;
        const size_t w = wrel >> 18;
        src = (w == 0) ? Wq : (w == 1) ? Wk : (w == 2) ? Wv : Wo;
        off = wrel & 262143;
        dst = Wb + wrel;
    }
    bf16x8 r;
    if (isf) {
        const float* f = (const float*)src + off;
#pragma unroll
        for (int j = 0; j < 8; ++j) r[j] = (__bf16)f[j];
    } else {
        r = *(const bf16x8*)((const __bf16*)src + off);
    }
    *(bf16x8*)dst = r;
}

// ---------------------------------------------------------------------------
// Kernel 2: fused QKV projection, 128x128 tile (2x2 waves of 64x64), BK=32,
// double-buffered LDS (32KB), single-barrier prefetch K-loop.
// grid (64, 12); by 0-3 Q (pre-scaled by QSCALE), 4-7 K, 8-11 V.
// V store: (b,h,dk,s) rows, key order PERMUTED within each 64-key chunk:
// value for key-in-chunk k = 16i + 4*quad + r, dk = 16j+lane16 is stored at
// col (quad + 4*(i>>1))*8 + (i&1)*4 + r.  Equivalently: 16B block
// b = (k>>5)*4 + ((k>>2)&3) holds keys {(k>>5)*32 + t*16 + ((k>>2)&3)*4 + r}
// at j = t*4+r -- exactly the k-slot order attn's register-built PV
// B-fragment uses (both in the old 64-key and new 32-key-half form).
// ---------------------------------------------------------------------------
__global__ __launch_bounds__(256)
void qkv_kernel(const __bf16* __restrict__ xb, const __bf16* __restrict__ Wb,
                const void* __restrict__ bq, const void* __restrict__ bk,
                const void* __restrict__ bv, const int* __restrict__ flag,
                __bf16* __restrict__ Q, __bf16* __restrict__ K,
                __bf16* __restrict__ Vt)
{
    __shared__ __align__(16) char smem[32768];   // 2 x (As 8KB | Bs 8KB)

    const int isf = *flag;
    const int tid = threadIdx.x;
    const int w = tid >> 6, l = tid & 63;
    const int lane16 = l & 15, quad = l >> 4;
    const int wm = w >> 1, wn = w & 1;
    const int m0 = blockIdx.x * 128;
    const int by = blockIdx.y;
    const int n0 = by * 128;

    const int cwl = w * 64 + l;
    const int g0 = (cwl & 3) ^ ((cwl >> 3) & 3);
    const __bf16* aS0 = xb + (size_t)(m0 + (cwl >> 2)) * D + g0 * 8;
    const __bf16* aS1 = aS0 + (size_t)64 * D;
    const __bf16* bS0 = Wb + (size_t)(n0 + (cwl >> 2)) * D + g0 * 8;
    const __bf16* bS1 = bS0 + (size_t)64 * D;

    const int sw = (quad ^ ((lane16 >> 1) & 3)) * 16;
    const int aoff = (wm * 64 + lane16) * 64 + sw;
    const int boff = 8192 + (wn * 64 + lane16) * 64 + sw;

    f32x4 acc[4][4];
#pragma unroll
    for (int i = 0; i < 4; ++i)
#pragma unroll
        for (int j = 0; j < 4; ++j) acc[i][j] = (f32x4){0,0,0,0};

    gload_lds16(aS0, smem + w * 1024);
    gload_lds16(aS1, smem + 4096 + w * 1024);
    gload_lds16(bS0, smem + 8192 + w * 1024);
    gload_lds16(bS1, smem + 12288 + w * 1024);

    for (int kt = 0; kt < D / 32; ++kt) {
        __syncthreads();

        const char* bufp = smem + (kt & 1) * 16384;
        if (kt + 1 < D / 32) {
            char* nb = smem + ((kt + 1) & 1) * 16384;
            gload_lds16(aS0 + (kt + 1) * 32, nb + w * 1024);
            gload_lds16(aS1 + (kt + 1) * 32, nb + 4096 + w * 1024);
            gload_lds16(bS0 + (kt + 1) * 32, nb + 8192 + w * 1024);
            gload_lds16(bS1 + (kt + 1) * 32, nb + 12288 + w * 1024);
        }

        bf16x8 af[4], bf[4];
#pragma unroll
        for (int i = 0; i < 4; ++i) af[i] = *(const bf16x8*)(bufp + aoff + i * 1024);
#pragma unroll
        for (int j = 0; j < 4; ++j) bf[j] = *(const bf16x8*)(bufp + boff + j * 1024);
#pragma unroll
        for (int i = 0; i < 4; ++i)
#pragma unroll
            for (int j = 0; j < 4; ++j)
                acc[i][j] = mfma16(af[i], bf[j], acc[i][j]);
    }

    const int which = by >> 2;           // block-uniform
    const int h = (by * 2 + wn) & 7;     // wave-uniform
    const float qs = (which == 0) ? QSCALE : 1.0f;
    const void* bias = (which == 0) ? bq : (which == 1) ? bk : bv;
    float bvv[4];
#pragma unroll
    for (int j = 0; j < 4; ++j)
        bvv[j] = ldf(bias, ((by & 3) * 128 + wn * 64 + 16 * j + lane16) & 511, isf);

    const int bb = m0 >> 11;             // batch (128-tiles never cross)
    const int ssb = (m0 & (S - 1)) + wm * 64;

    if (which < 2) {
        __bf16* out = ((which == 0) ? Q : K) + ((size_t)(bb * NH + h) * S) * DK;
#pragma unroll
        for (int i = 0; i < 4; ++i)
#pragma unroll
            for (int r = 0; r < 4; ++r) {
                const int ss = ssb + i * 16 + quad * 4 + r;
#pragma unroll
                for (int j = 0; j < 4; ++j)
                    out[(size_t)ss * DK + 16 * j + lane16] =
                        (__bf16)((acc[i][j][r] + bvv[j]) * qs);
            }
    } else {
        // V store, key-permuted within the 64-key chunk (ssb is 64-aligned).
#pragma unroll
        for (int i = 0; i < 4; ++i)
#pragma unroll
            for (int j = 0; j < 4; ++j) {
                const int dkc = 16 * j + lane16;
                __bf16* vp = Vt + ((size_t)(bb * NH + h) * DK + dkc) * S
                                + ssb + (quad + 4 * (i >> 1)) * 8 + 4 * (i & 1);
                bf16x4 pkt;
#pragma unroll
                for (int r = 0; r < 4; ++r) pkt[r] = (__bf16)(acc[i][j][r] + bvv[j]);
                *(bf16x4*)vp = pkt;
            }
    }
}

// ---------------------------------------------------------------------------
// Kernel 3: flash attention, 64-key chunks, q_w=64 / k_w=32 decomposition:
// 8 waves = (2 query-groups of 64q) x (2 key-halves of 32k) x (2 chunk-
// parity teams).  LDS-read bytes scale as 1/q_w, so q_w 32->64 HALVES the
// measured LDS traffic (8 ds_read_b128 per wave-chunk vs 16).  With
// k_w=32, PV is ONE K=32 MFMA per (u,tt); the key-permuted V store means
// each wave's 32 keys live in LDS blocks kh*4+quad and the PV B-fragment
// packs directly from st (register-P, zero cross-lane).  l is accumulated
// on the VALU from the SAME TRUNCATED bf16 values (extracted from packed
// words), preserving numerator/denominator identity.  Epilogue: per
// query-group 4-partial merge (l via 2KB LDS; o via two-stage 64+32KB
// merge in the dead buffers).  LDS 64KB -> 2 blocks/CU, 4 waves/SIMD.
// ---------------------------------------------------------------------------
__global__ __launch_bounds__(512, 4)
void attn_kernel(const __bf16* __restrict__ Q, const __bf16* __restrict__ K,
                 const __bf16* __restrict__ Vt, __bf16* __restrict__ ctx)
{
    __shared__ __align__(16) char smem[65536];   // 4 x [K 8KB | V 8KB]

    const int tid = threadIdx.x;
    const int w = tid >> 6, l = tid & 63;
    const int lane16 = l & 15, quad = l >> 4;
    const int qg = w & 1, kh = (w >> 1) & 1, team = w >> 2;

    const int lin = blockIdx.x;
    const int xcd = lin & 7;
    const int t = lin >> 3;             // 0..63
    const int bh = xcd * 4 + (t >> 4);
    const int qt = t & 15;              // 128-query block within (b,h)
    const int b = bh >> 3, h = bh & 7;
    const size_t bhS = (size_t)bh * S;

    // staging sources: slot s = w*64+l (0..511): row = s>>3 (0..63),
    // phys granule s&7 holds data granule (s&7)^(row&7).
    const int cwl = w * 64 + l;
    const int row = cwl >> 3;
    const int g = (cwl & 7) ^ (row & 7);
    const char* kS = (const char*)(K + (bhS + row) * DK) + g * 16;
    const char* vS = (const char*)(Vt + ((size_t)bh * DK + row) * S) + g * 16;

    // Q fragments: 4 q-tiles of 16 (64 queries per wave)
    const int qbase = qt * 128 + qg * 64;
    bf16x8 qa[4][2];
#pragma unroll
    for (int u = 0; u < 4; ++u) {
        const __bf16* Qp = Q + (bhS + qbase + u * 16 + lane16) * DK + quad * 8;
        qa[u][0] = ldg8(Qp);
        qa[u][1] = ldg8(Qp + 32);
    }

    const int x7 = lane16 & 7;
    const int krow0 = kh * 4096 + lane16 * 128;        // + kt2*2048
    const int vblk = ((kh * 4 + quad) ^ x7) * 16;

    f32x4 o[4][4];
    float l4[4] = {0.f, 0.f, 0.f, 0.f};
#pragma unroll
    for (int u = 0; u < 4; ++u)
#pragma unroll
        for (int tt = 0; tt < 4; ++tt) o[u][tt] = (f32x4){0,0,0,0};

    // prologue: stage chunk 0 -> buf 0, chunk 1 -> buf 2
    gload_lds16(kS, smem + w * 1024);
    gload_lds16(vS, smem + 8192 + w * 1024);
    gload_lds16(kS + 8192, smem + 32768 + w * 1024);
    gload_lds16(vS + 128, smem + 32768 + 8192 + w * 1024);

    for (int p = 0; p < S / 128; ++p) {  // 16 periods, 2 chunks each
        __syncthreads();                 // chunks 2p, 2p+1 staged & visible

        const char* kb = smem + (team * 2 + (p & 1)) * 16384;
        const char* vb = kb + 8192;

        if (p + 1 < S / 128) {           // prefetch chunks 2p+2, 2p+3
            const int ns = (p + 1) & 1;
            const size_t c1 = 2 * p + 2, c2 = 2 * p + 3;
            char* b1 = smem + ns * 16384;
            char* b2 = smem + (2 + ns) * 16384;
            gload_lds16(kS + c1 * 8192, b1 + w * 1024);
            gload_lds16(vS + c1 * 128,  b1 + 8192 + w * 1024);
            gload_lds16(kS + c2 * 8192, b2 + w * 1024);
            gload_lds16(vS + c2 * 128,  b2 + 8192 + w * 1024);
        }

        // QK^T over this wave's 32-key half; bp built in registers.
        u32x4 bw[4];
#pragma unroll
        for (int kt2 = 0; kt2 < 2; ++kt2) {
            const int base = krow0 + kt2 * 2048;
            const bf16x8 kfA = *(const bf16x8*)(kb + base + ((quad ^ x7) * 16));
            const bf16x8 kfB = *(const bf16x8*)(kb + base
                                                + (((quad + 4) ^ x7) * 16));
            f32x4 stv[4];
            __builtin_amdgcn_s_setprio(1);
#pragma unroll
            for (int u = 0; u < 4; ++u) {
                f32x4 z = {0,0,0,0};
                z = mfma16(kfA, qa[u][0], z);
                stv[u] = mfma16(kfB, qa[u][1], z);
            }
            __builtin_amdgcn_s_setprio(0);
#pragma unroll
            for (int u = 0; u < 4; ++u) {
                const unsigned w0 = pack_trunc(fexp2(stv[u][0]), fexp2(stv[u][1]));
                const unsigned w1 = pack_trunc(fexp2(stv[u][2]), fexp2(stv[u][3]));
                bw[u][kt2 * 2]     = w0;
                bw[u][kt2 * 2 + 1] = w1;
                // l from the SAME truncated values (numerator identity)
                l4[u] += __builtin_bit_cast(float, w0 << 16)
                       + __builtin_bit_cast(float, w0 & 0xFFFF0000u)
                       + __builtin_bit_cast(float, w1 << 16)
                       + __builtin_bit_cast(float, w1 & 0xFFFF0000u);
            }
        }

        // V fragments for this key-half (blocks kh*4+quad) + PV
        bf16x8 vA[4];
#pragma unroll
        for (int tt = 0; tt < 4; ++tt)
            vA[tt] = *(const bf16x8*)(vb + (tt * 16 + lane16) * 128 + vblk);

        __builtin_amdgcn_s_setprio(1);
#pragma unroll
        for (int u = 0; u < 4; ++u) {
            const bf16x8 bp = __builtin_bit_cast(bf16x8, bw[u]);
#pragma unroll
            for (int tt = 0; tt < 4; ++tt)
                o[u][tt] = mfma16(vA[tt], bp, o[u][tt]);
        }
        __builtin_amdgcn_s_setprio(0);
    }

    // ---- epilogue: merge 4 partials (kh x team) per query-group ----
    __syncthreads();
    // l: reduce over quads, publish, owners sum 4 partials
#pragma unroll
    for (int u = 0; u < 4; ++u) {
        l4[u] += __shfl_xor(l4[u], 16);
        l4[u] += __shfl_xor(l4[u], 32);
    }
    if (quad == 0) {
        float* lp = (float*)(smem + w * 256 + lane16 * 16);
#pragma unroll
        for (int u = 0; u < 4; ++u) lp[u] = l4[u];
    }
    __syncthreads();
    float inv[4];
    if (team == 0 && kh == 0) {
#pragma unroll
        for (int u = 0; u < 4; ++u) {
            const float s = l4[u]
                + *(const float*)(smem + (w + 2) * 256 + lane16 * 16 + u * 4)
                + *(const float*)(smem + (w + 4) * 256 + lane16 * 16 + u * 4)
                + *(const float*)(smem + (w + 6) * 256 + lane16 * 16 + u * 4);
            inv[u] = 1.0f / s;
        }
    }
    __syncthreads();
    // o merge stage 1: team 1 writes region (qg*2+kh); team 0 adds
    if (team == 1) {
        char* rg = smem + (qg * 2 + kh) * 16384;
#pragma unroll
        for (int u = 0; u < 4; ++u)
#pragma unroll
            for (int tt = 0; tt < 4; ++tt)
                *(f32x4*)(rg + (u * 4 + tt) * 1024 + l * 16) = o[u][tt];
    }
    __syncthreads();
    if (team == 0) {
        const char* rg = smem + (qg * 2 + kh) * 16384;
#pragma unroll
        for (int u = 0; u < 4; ++u)
#pragma unroll
            for (int tt = 0; tt < 4; ++tt)
                o[u][tt] += *(const f32x4*)(rg + (u * 4 + tt) * 1024 + l * 16);
    }
    __syncthreads();
    // stage 2: (team0, kh1) writes region qg; owner (team0, kh0) finishes
    if (team == 0 && kh == 1) {
        char* rg = smem + qg * 16384;
#pragma unroll
        for (int u = 0; u < 4; ++u)
#pragma unroll
            for (int tt = 0; tt < 4; ++tt)
                *(f32x4*)(rg + (u * 4 + tt) * 1024 + l * 16) = o[u][tt];
    }
    __syncthreads();
    if (team == 0 && kh == 0) {
        const char* rg = smem + qg * 16384;
#pragma unroll
        for (int u = 0; u < 4; ++u) {
            __bf16* cp = ctx + ((size_t)(b * S + qbase + u * 16 + lane16)) * D
                         + h * DK;
#pragma unroll
            for (int tt = 0; tt < 4; ++tt) {
                const f32x4 po = *(const f32x4*)(rg + (u * 4 + tt) * 1024
                                                 + l * 16);
                bf16x4 pkt;
#pragma unroll
                for (int r = 0; r < 4; ++r)
                    pkt[r] = (__bf16)((o[u][tt][r] + po[r]) * inv[u]);
                *(bf16x4*)(cp + tt * 16 + quad * 4) = pkt;
            }
        }
    }
}

// ---------------------------------------------------------------------------
// Kernel 4: FUSED output projection + bias + residual + LayerNorm -> d_out.
// Block = 16 tokens x FULL 512 cols; grid 512 x 512 threads; see R8.
// ---------------------------------------------------------------------------
__global__ __launch_bounds__(512)
void proj_ln_kernel(const __bf16* __restrict__ ctx, const __bf16* __restrict__ Wb,
                    const void* __restrict__ bo, const __bf16* __restrict__ xb,
                    const void* __restrict__ gamma, const void* __restrict__ beta,
                    const int* __restrict__ flag, void* __restrict__ out)
{
    __shared__ __align__(16) char smem[67584];   // 2 x (A 1KB | B 32KB)

    const int isf = *flag;
    const int tid = threadIdx.x;
    const int w = tid >> 6, l = tid & 63;
    const int lane16 = l & 15, quad = l >> 4;
    const int m0 = blockIdx.x * 16;

    const __bf16* Wo = Wb + (size_t)3 * 262144;
    const int cwl = tid;

    // A staging (wave 0 only): slots 0..63, row = s>>2, granule swizzled
    const int gA = (cwl & 3) ^ ((cwl >> 3) & 3);
    const __bf16* aS = ctx + (size_t)(m0 + ((cwl & 63) >> 2)) * D + gA * 8;

    // B staging: slots c*512 + cwl (c = 0..3), row = s>>2 (0..511)
    const __bf16* bS[4];
#pragma unroll
    for (int c = 0; c < 4; ++c) {
        const int s = c * 512 + cwl;
        const int gB = (s & 3) ^ ((s >> 3) & 3);
        bS[c] = Wo + (size_t)(s >> 2) * D + gB * 8;
    }

    const int sw = (quad ^ ((lane16 >> 1) & 3)) * 16;
    const int aoff = lane16 * 64 + sw;                       // A row = lane16
    const int boff = 1024 + (w * 64 + lane16) * 64 + sw;     // B row = col

    f32x4 acc[4];
#pragma unroll
    for (int j = 0; j < 4; ++j) acc[j] = (f32x4){0,0,0,0};

    // prologue: stage kt=0 into buf 0
    if (w == 0) gload_lds16(aS, smem);
#pragma unroll
    for (int c = 0; c < 4; ++c)
        gload_lds16(bS[c], smem + 1024 + c * 8192 + w * 1024);

    for (int kt = 0; kt < D / 32; ++kt) {
        __syncthreads();

        const char* bufp = smem + (kt & 1) * 33792;
        if (kt + 1 < D / 32) {
            char* nb = smem + ((kt + 1) & 1) * 33792;
            if (w == 0) gload_lds16(aS + (kt + 1) * 32, nb);
#pragma unroll
            for (int c = 0; c < 4; ++c)
                gload_lds16(bS[c] + (kt + 1) * 32,
                            nb + 1024 + c * 8192 + w * 1024);
        }

        const bf16x8 af = *(const bf16x8*)(bufp + aoff);
        bf16x8 bf[4];
#pragma unroll
        for (int j = 0; j < 4; ++j) bf[j] = *(const bf16x8*)(bufp + boff + j * 1024);
#pragma unroll
        for (int j = 0; j < 4; ++j)
            acc[j] = mfma16(af, bf[j], acc[j]);
    }

    // ---- epilogue: bias + residual (fp32), then in-block LayerNorm ----
    float bvv[4], gv[4], bev[4];
#pragma unroll
    for (int j = 0; j < 4; ++j) {
        const int col = w * 64 + 16 * j + lane16;
        bvv[j] = ldf(bo, col, isf);
        gv[j]  = ldf(gamma, col, isf);
        bev[j] = ldf(beta, col, isf);
    }

    // v[r][j] = acc + bias + x  (cached in regs; 16 floats)
    float v[4][4];
#pragma unroll
    for (int r = 0; r < 4; ++r) {
        const int tok = m0 + quad * 4 + r;
#pragma unroll
        for (int j = 0; j < 4; ++j) {
            const int col = w * 64 + 16 * j + lane16;
            v[r][j] = acc[j][r] + bvv[j] + (float)xb[(size_t)tok * D + col];
        }
    }

    // per-wave 64-col partials: reduce over lane16 (4-step shfl_xor)
#pragma unroll
    for (int r = 0; r < 4; ++r) {
        float s1 = v[r][0] + v[r][1] + v[r][2] + v[r][3];
        float s2 = v[r][0]*v[r][0] + v[r][1]*v[r][1]
                 + v[r][2]*v[r][2] + v[r][3]*v[r][3];
#pragma unroll
        for (int msk = 1; msk < 16; msk <<= 1) {
            s1 += __shfl_xor(s1, msk);
            s2 += __shfl_xor(s2, msk);
        }
        if (lane16 == 0) {
            // partial[w][row] in dead buf-0 region (last compute used buf 1)
            float* pp = (float*)(smem + ((w * 16 + quad * 4 + r) * 8));
            pp[0] = s1;
            pp[1] = s2;
        }
    }
    __syncthreads();

    // cross-wave reduce: 16 tokens, thread t<16 sums 8 wave-partials
    if (tid < 16) {
        float s1 = 0.f, s2 = 0.f;
#pragma unroll
        for (int ww = 0; ww < 8; ++ww) {
            const float* pp = (const float*)(smem + ((ww * 16 + tid) * 8));
            s1 += pp[0];
            s2 += pp[1];
        }
        const float mean = s1 * (1.0f / D);
        const float var  = s2 * (1.0f / D) - mean * mean;
        float* st = (float*)(smem + 2048 + tid * 8);
        st[0] = mean;
        st[1] = rsqrtf(var + 1e-5f);
    }
    __syncthreads();

    // normalize + write
#pragma unroll
    for (int r = 0; r < 4; ++r) {
        const int row = quad * 4 + r;
        const float* st = (const float*)(smem + 2048 + row * 8);
        const float mean = st[0], rstd = st[1];
        const size_t tb = (size_t)(m0 + row) * D;
#pragma unroll
        for (int j = 0; j < 4; ++j) {
            const int col = w * 64 + 16 * j + lane16;
            const float res = (v[r][j] - mean) * rstd * gv[j] + bev[j];
            if (isf) ((float*)out)[tb + col] = res;
            else     ((__bf16*)out)[tb + col] = (__bf16)res;
        }
    }
}

// ---------------------------------------------------------------------------
extern "C" void kernel_launch(void* const* d_in, const int* in_sizes, int n_in,
                              void* d_out, int out_size, void* d_ws,
                              size_t ws_size, hipStream_t stream)
{
    const void* x     = d_in[0];
    const void* Wq    = d_in[1];
    const void* bq    = d_in[2];
    const void* Wk    = d_in[3];
    const void* bk    = d_in[4];
    const void* Wv    = d_in[5];
    const void* bv    = d_in[6];
    const void* Wo    = d_in[7];
    const void* bo    = d_in[8];
    const void* gamma = d_in[9];
    const void* beta  = d_in[10];

    char* ws = (char*)d_ws;
    __bf16* xb  = (__bf16*)(ws + OFF_XB);
    __bf16* Wb  = (__bf16*)(ws + OFF_WB);
    __bf16* Qb  = (__bf16*)(ws + OFF_Q);
    __bf16* Kb  = (__bf16*)(ws + OFF_K);
    __bf16* Vtb = (__bf16*)(ws + OFF_VT);
    __bf16* ctx = (__bf16*)(ws + OFF_CTX);
    int*    flag = (int*)(ws + OFF_FLAG);

    cvt_kernel<<<5242880 / (256 * 8), 256, 0, stream>>>(
        x, Wq, Wk, Wv, Wo, xb, Wb, flag);
    qkv_kernel<<<dim3(N_TOK / 128, 12), 256, 0, stream>>>(
        xb, Wb, bq, bk, bv, flag, Qb, Kb, Vtb);
    attn_kernel<<<dim3(512), 512, 0, stream>>>(Qb, Kb, Vtb, ctx);
    proj_ln_kernel<<<dim3(N_TOK / 16), 512, 0, stream>>>(
        ctx, Wb, bo, xb, gamma, beta, flag, d_out);
}

// Round 10
// 166.903 us; speedup vs baseline: 1.8399x; 1.8399x over previous
//
#include <hip/hip_runtime.h>
#include <math.h>

// Problem constants
#define D 512
#define NH 8
#define DK 64
#define S 2048
#define BATCH 4
#define N_TOK (BATCH * S)   // 8192

// fold 1/sqrt(dk) * log2(e) into Q so softmax numerator is exp2(q.k)
#define QSCALE 0.18033688f  // 0.125 * 1.4426950408889634

typedef __bf16 bf16x8 __attribute__((ext_vector_type(8)));
typedef __bf16 bf16x4 __attribute__((ext_vector_type(4)));
typedef float f32x4 __attribute__((ext_vector_type(4)));
typedef unsigned int u32x4 __attribute__((ext_vector_type(4)));

#define AS1 __attribute__((address_space(1)))
#define AS3 __attribute__((address_space(3)))

// Workspace layout (bytes):
//   [0,        8388608)   xb   bf16 (N_TOK, D)
//   [8388608, 10485760)   Wb   bf16 Wq|Wk|Wv|Wo stacked, (2048, 512)
//   [10485760,18874368)   Q    bf16 (b,h,s,dk)
//   [18874368,27262976)   K    bf16 (b,h,s,dk)
//   [27262976,35651584)   Vt   bf16 (b,h,dk,s) with keys PERMUTED within
//                              each 64-key chunk (see qkv V-store)
//   [35651584,44040192)   ctx  bf16 (tok, D)
//   [44040192,44040196)   flag int (1 = device buffers are fp32)
#define OFF_XB   0
#define OFF_WB   8388608
#define OFF_Q    10485760
#define OFF_K    18874368
#define OFF_VT   27262976
#define OFF_CTX  35651584
#define OFF_FLAG 44040192

static __device__ __forceinline__ bf16x8 ldg8(const __bf16* p) {
    return *(const bf16x8*)p;
}
static __device__ __forceinline__ f32x4 mfma16(bf16x8 a, bf16x8 b, f32x4 c) {
    return __builtin_amdgcn_mfma_f32_16x16x32_bf16(a, b, c, 0, 0, 0);
}
static __device__ __forceinline__ float ldf(const void* p, size_t i, int isf) {
    return isf ? ((const float*)p)[i] : (float)(((const __bf16*)p)[i]);
}
static __device__ __forceinline__ float fexp2(float x) {
#if __has_builtin(__builtin_amdgcn_exp2f)
    return __builtin_amdgcn_exp2f(x);   // bare v_exp_f32
#else
    return exp2f(x);
#endif
}
// pack hi16(e0) | hi16(e1)<<16  (bf16 truncation; folds to v_perm_b32)
static __device__ __forceinline__ unsigned pack_trunc(float e0, float e1) {
    return (__builtin_bit_cast(unsigned, e0) >> 16)
         | (__builtin_bit_cast(unsigned, e1) & 0xFFFF0000u);
}
// async global->LDS, 16B/lane; lds base wave-uniform, HW adds lane*16.
static __device__ __forceinline__ void gload_lds16(const void* g, void* l) {
    __builtin_amdgcn_global_load_lds((const AS1 char*)g, (AS3 char*)l, 16, 0, 0);
}

// ---------------------------------------------------------------------------
// Kernel 1: convert x and Wq|Wk|Wv|Wo to bf16 in ws. Self-detects dtype
// (wave-level probe of x interpreted as bf16: fp32 bit-soup gives |v|>64 or
// NaN with certainty over 512 samples); block 0 publishes flag downstream.
// ---------------------------------------------------------------------------
__global__ __launch_bounds__(256)
void cvt_kernel(const void* __restrict__ x,  const void* __restrict__ Wq,
                const void* __restrict__ Wk, const void* __restrict__ Wv,
                const void* __restrict__ Wo, __bf16* __restrict__ xb,
                __bf16* __restrict__ Wb, int* __restrict__ flag)
{
    // wave-uniform dtype probe
    const bf16x8 probe = ldg8((const __bf16*)x + (threadIdx.x & 63) * 8);
    int bad = 0;
#pragma unroll
    for (int j = 0; j < 8; ++j) bad |= !(fabsf((float)probe[j]) <= 64.0f);
    const int isf = __any(bad) ? 1 : 0;
    if (blockIdx.x == 0 && threadIdx.x == 0) *flag = isf;

    const size_t i0 = ((size_t)blockIdx.x * 256 + threadIdx.x) * 8;
    const void* src;
    __bf16* dst;
    size_t off;
    if (i0 < 4194304) {
        src = x; off = i0; dst = xb + i0;
    } else {
        const size_t wrel = i0 - 4194304;
        const size_t w = wrel >> 18;
        src = (w == 0) ? Wq : (w == 1) ? Wk : (w == 2) ? Wv : Wo;
        off = wrel & 262143;
        dst = Wb + wrel;
    }
    bf16x8 r;
    if (isf) {
        const float* f = (const float*)src + off;
#pragma unroll
        for (int j = 0; j < 8; ++j) r[j] = (__bf16)f[j];
    } else {
        r = *(const bf16x8*)((const __bf16*)src + off);
    }
    *(bf16x8*)dst = r;
}

// ---------------------------------------------------------------------------
// Kernel 2: fused QKV projection, 128x128 tile (2x2 waves of 64x64), BK=32,
// double-buffered LDS (32KB), single-barrier prefetch K-loop.
// grid (64, 12); by 0-3 Q (pre-scaled by QSCALE), 4-7 K, 8-11 V.
// V store: (b,h,dk,s) rows, key order PERMUTED within each 64-key chunk:
// col-in-chunk for key k = 16i + 4*quad + r  is  (quad + 4*(i>>1))*8 +
// 4*(i&1) + r, so attn's PV B-fragment is built in registers.
// ---------------------------------------------------------------------------
__global__ __launch_bounds__(256)
void qkv_kernel(const __bf16* __restrict__ xb, const __bf16* __restrict__ Wb,
                const void* __restrict__ bq, const void* __restrict__ bk,
                const void* __restrict__ bv, const int* __restrict__ flag,
                __bf16* __restrict__ Q, __bf16* __restrict__ K,
                __bf16* __restrict__ Vt)
{
    __shared__ __align__(16) char smem[32768];   // 2 x (As 8KB | Bs 8KB)

    const int isf = *flag;
    const int tid = threadIdx.x;
    const int w = tid >> 6, l = tid & 63;
    const int lane16 = l & 15, quad = l >> 4;
    const int wm = w >> 1, wn = w & 1;
    const int m0 = blockIdx.x * 128;
    const int by = blockIdx.y;
    const int n0 = by * 128;

    const int cwl = w * 64 + l;
    const int g0 = (cwl & 3) ^ ((cwl >> 3) & 3);
    const __bf16* aS0 = xb + (size_t)(m0 + (cwl >> 2)) * D + g0 * 8;
    const __bf16* aS1 = aS0 + (size_t)64 * D;
    const __bf16* bS0 = Wb + (size_t)(n0 + (cwl >> 2)) * D + g0 * 8;
    const __bf16* bS1 = bS0 + (size_t)64 * D;

    const int sw = (quad ^ ((lane16 >> 1) & 3)) * 16;
    const int aoff = (wm * 64 + lane16) * 64 + sw;
    const int boff = 8192 + (wn * 64 + lane16) * 64 + sw;

    f32x4 acc[4][4];
#pragma unroll
    for (int i = 0; i < 4; ++i)
#pragma unroll
        for (int j = 0; j < 4; ++j) acc[i][j] = (f32x4){0,0,0,0};

    gload_lds16(aS0, smem + w * 1024);
    gload_lds16(aS1, smem + 4096 + w * 1024);
    gload_lds16(bS0, smem + 8192 + w * 1024);
    gload_lds16(bS1, smem + 12288 + w * 1024);

    for (int kt = 0; kt < D / 32; ++kt) {
        __syncthreads();

        const char* bufp = smem + (kt & 1) * 16384;
        if (kt + 1 < D / 32) {
            char* nb = smem + ((kt + 1) & 1) * 16384;
            gload_lds16(aS0 + (kt + 1) * 32, nb + w * 1024);
            gload_lds16(aS1 + (kt + 1) * 32, nb + 4096 + w * 1024);
            gload_lds16(bS0 + (kt + 1) * 32, nb + 8192 + w * 1024);
            gload_lds16(bS1 + (kt + 1) * 32, nb + 12288 + w * 1024);
        }

        bf16x8 af[4], bf[4];
#pragma unroll
        for (int i = 0; i < 4; ++i) af[i] = *(const bf16x8*)(bufp + aoff + i * 1024);
#pragma unroll
        for (int j = 0; j < 4; ++j) bf[j] = *(const bf16x8*)(bufp + boff + j * 1024);
#pragma unroll
        for (int i = 0; i < 4; ++i)
#pragma unroll
            for (int j = 0; j < 4; ++j)
                acc[i][j] = mfma16(af[i], bf[j], acc[i][j]);
    }

    const int which = by >> 2;           // block-uniform
    const int h = (by * 2 + wn) & 7;     // wave-uniform
    const float qs = (which == 0) ? QSCALE : 1.0f;
    const void* bias = (which == 0) ? bq : (which == 1) ? bk : bv;
    float bvv[4];
#pragma unroll
    for (int j = 0; j < 4; ++j)
        bvv[j] = ldf(bias, ((by & 3) * 128 + wn * 64 + 16 * j + lane16) & 511, isf);

    const int bb = m0 >> 11;             // batch (128-tiles never cross)
    const int ssb = (m0 & (S - 1)) + wm * 64;

    if (which < 2) {
        __bf16* out = ((which == 0) ? Q : K) + ((size_t)(bb * NH + h) * S) * DK;
#pragma unroll
        for (int i = 0; i < 4; ++i)
#pragma unroll
            for (int r = 0; r < 4; ++r) {
                const int ss = ssb + i * 16 + quad * 4 + r;
#pragma unroll
                for (int j = 0; j < 4; ++j)
                    out[(size_t)ss * DK + 16 * j + lane16] =
                        (__bf16)((acc[i][j][r] + bvv[j]) * qs);
            }
    } else {
        // V store, key-permuted within the 64-key chunk (ssb is 64-aligned).
#pragma unroll
        for (int i = 0; i < 4; ++i)
#pragma unroll
            for (int j = 0; j < 4; ++j) {
                const int dkc = 16 * j + lane16;
                __bf16* vp = Vt + ((size_t)(bb * NH + h) * DK + dkc) * S
                                + ssb + (quad + 4 * (i >> 1)) * 8 + 4 * (i & 1);
                bf16x4 pkt;
#pragma unroll
                for (int r = 0; r < 4; ++r) pkt[r] = (__bf16)(acc[i][j][r] + bvv[j]);
                *(bf16x4*)vp = pkt;
            }
    }
}

// ---------------------------------------------------------------------------
// Kernel 3: flash attention, key-split teams (q_w=32 -- the register-
// feasible corner: q_w=64 spills past the 128-VGPR cap, R9).  8 waves =
// 2 teams x 4 waves; team 0 even chunks, team 1 odd; 32 queries per wave.
// Register-P via key-permuted V; s_setprio(1) around MFMA clusters.
// LDS: 4 x [K 8KB | V 8KB] = 64KB -> 2 blocks/CU, 4 waves/SIMD.
// ---------------------------------------------------------------------------
__global__ __launch_bounds__(512, 4)
void attn_kernel(const __bf16* __restrict__ Q, const __bf16* __restrict__ K,
                 const __bf16* __restrict__ Vt, __bf16* __restrict__ ctx)
{
    __shared__ __align__(16) char smem[65536];   // 4 x [K 8KB | V 8KB]

    const int tid = threadIdx.x;
    const int w = tid >> 6, l = tid & 63;
    const int lane16 = l & 15, quad = l >> 4;
    const int team = w >> 2, tq = w & 3;

    const int lin = blockIdx.x;
    const int xcd = lin & 7;
    const int t = lin >> 3;             // 0..63
    const int bh = xcd * 4 + (t >> 4);
    const int qt = t & 15;              // 128-query block within (b,h)
    const int b = bh >> 3, h = bh & 7;
    const size_t bhS = (size_t)bh * S;

    const int cwl = w * 64 + l;
    const int row = cwl >> 3;
    const int g = (cwl & 7) ^ (row & 7);
    const char* kS = (const char*)(K + (bhS + row) * DK) + g * 16;
    const char* vS = (const char*)(Vt + ((size_t)bh * DK + row) * S) + g * 16;

    const int qbase = qt * 128 + tq * 32;
    bf16x8 qa[2][2];
#pragma unroll
    for (int u = 0; u < 2; ++u) {
        const __bf16* Qp = Q + (bhS + qbase + u * 16 + lane16) * DK + quad * 8;
        qa[u][0] = ldg8(Qp);
        qa[u][1] = ldg8(Qp + 32);
    }

    bf16x8 aones;
#pragma unroll
    for (int j = 0; j < 8; ++j) aones[j] = (__bf16)1.0f;

    const int x7 = lane16 & 7;

    f32x4 o[2][4], lacc[2];
#pragma unroll
    for (int u = 0; u < 2; ++u) {
        lacc[u] = (f32x4){0,0,0,0};
#pragma unroll
        for (int tt = 0; tt < 4; ++tt) o[u][tt] = (f32x4){0,0,0,0};
    }

    // prologue: stage chunk 0 -> buf 0, chunk 1 -> buf 2
    gload_lds16(kS, smem + w * 1024);
    gload_lds16(vS, smem + 8192 + w * 1024);
    gload_lds16(kS + 8192, smem + 32768 + w * 1024);
    gload_lds16(vS + 128, smem + 32768 + 8192 + w * 1024);

    for (int p = 0; p < S / 128; ++p) {  // 16 periods, 2 chunks each
        __syncthreads();                 // chunks 2p, 2p+1 staged & visible

        const char* kb = smem + (team * 2 + (p & 1)) * 16384;
        const char* vb = kb + 8192;

        if (p + 1 < S / 128) {           // prefetch chunks 2p+2, 2p+3
            const int ns = (p + 1) & 1;
            const size_t c1 = 2 * p + 2, c2 = 2 * p + 3;
            char* b1 = smem + ns * 16384;
            char* b2 = smem + (2 + ns) * 16384;
            gload_lds16(kS + c1 * 8192, b1 + w * 1024);
            gload_lds16(vS + c1 * 128,  b1 + 8192 + w * 1024);
            gload_lds16(kS + c2 * 8192, b2 + w * 1024);
            gload_lds16(vS + c2 * 128,  b2 + 8192 + w * 1024);
        }

        // QK^T: K fragments transient per key-tile.
        f32x4 st[2][4];
#pragma unroll
        for (int tt = 0; tt < 4; ++tt) {
            const int base = (tt * 16 + lane16) * 128;
            const bf16x8 kfA = *(const bf16x8*)(kb + base + ((quad ^ x7) * 16));
            const bf16x8 kfB = *(const bf16x8*)(kb + base
                                                + (((quad + 4) ^ x7) * 16));
            __builtin_amdgcn_s_setprio(1);
#pragma unroll
            for (int u = 0; u < 2; ++u) {
                f32x4 z = {0,0,0,0};
                z = mfma16(kfA, qa[u][0], z);
                st[u][tt] = mfma16(kfB, qa[u][1], z);
            }
            __builtin_amdgcn_s_setprio(0);
        }

        // exp2 + pack straight into PV B-fragments (registers)
        bf16x8 bp[2][2];
#pragma unroll
        for (int u = 0; u < 2; ++u) {
            u32x4 u0, u1;
            u0[0] = pack_trunc(fexp2(st[u][0][0]), fexp2(st[u][0][1]));
            u0[1] = pack_trunc(fexp2(st[u][0][2]), fexp2(st[u][0][3]));
            u0[2] = pack_trunc(fexp2(st[u][1][0]), fexp2(st[u][1][1]));
            u0[3] = pack_trunc(fexp2(st[u][1][2]), fexp2(st[u][1][3]));
            u1[0] = pack_trunc(fexp2(st[u][2][0]), fexp2(st[u][2][1]));
            u1[1] = pack_trunc(fexp2(st[u][2][2]), fexp2(st[u][2][3]));
            u1[2] = pack_trunc(fexp2(st[u][3][0]), fexp2(st[u][3][1]));
            u1[3] = pack_trunc(fexp2(st[u][3][2]), fexp2(st[u][3][3]));
            bp[u][0] = __builtin_bit_cast(bf16x8, u0);
            bp[u][1] = __builtin_bit_cast(bf16x8, u1);
        }

        // V fragments + PV + l
#pragma unroll
        for (int tt = 0; tt < 4; ++tt) {
            const int base = (tt * 16 + lane16) * 128;
            const bf16x8 vA = *(const bf16x8*)(vb + base + ((quad ^ x7) * 16));
            const bf16x8 vB = *(const bf16x8*)(vb + base
                                               + (((quad + 4) ^ x7) * 16));
            __builtin_amdgcn_s_setprio(1);
#pragma unroll
            for (int u = 0; u < 2; ++u) {
                o[u][tt] = mfma16(vA, bp[u][0], o[u][tt]);
                o[u][tt] = mfma16(vB, bp[u][1], o[u][tt]);
            }
            __builtin_amdgcn_s_setprio(0);
        }
        __builtin_amdgcn_s_setprio(1);
#pragma unroll
        for (int u = 0; u < 2; ++u) {
            lacc[u] = mfma16(aones, bp[u][0], lacc[u]);
            lacc[u] = mfma16(aones, bp[u][1], lacc[u]);
        }
        __builtin_amdgcn_s_setprio(0);
    }

    // team merge: O = OA + OB, l = lA + lB (no-max softmax sums are exact).
    __syncthreads();
    if (team == 1) {
        char* obase = smem + tq * 8192;
#pragma unroll
        for (int u = 0; u < 2; ++u)
#pragma unroll
            for (int tt = 0; tt < 4; ++tt)
                *(f32x4*)(obase + (u * 4 + tt) * 1024 + l * 16) = o[u][tt];
        float* lb = (float*)(smem + 32768 + tq * 512 + l * 8);
        lb[0] = lacc[0][0];
        lb[1] = lacc[1][0];
    }
    __syncthreads();
    if (team == 0) {
        const char* obase = smem + tq * 8192;
        const float* lb = (const float*)(smem + 32768 + tq * 512 + l * 8);
#pragma unroll
        for (int u = 0; u < 2; ++u) {
            const float inv = 1.0f / (lacc[u][0] + lb[u]);
            __bf16* cp = ctx + ((size_t)(b * S + qbase + u * 16 + lane16)) * D
                         + h * DK;
#pragma unroll
            for (int tt = 0; tt < 4; ++tt) {
                const f32x4 po = *(const f32x4*)(obase + (u * 4 + tt) * 1024
                                                 + l * 16);
                bf16x4 pkt;
#pragma unroll
                for (int r = 0; r < 4; ++r)
                    pkt[r] = (__bf16)((o[u][tt][r] + po[r]) * inv);
                *(bf16x4*)(cp + tt * 16 + quad * 4) = pkt;
            }
        }
    }
}

// ---------------------------------------------------------------------------
// Kernel 4: FUSED output projection + bias + residual + LayerNorm -> d_out.
// Block = 16 tokens x FULL 512 cols (so LN rows never cross blocks).
// grid 512 x 512 threads (8 waves; wave w owns cols w*64..w*64+63) ->
// 2 blocks/CU, 16 waves/CU.  Per K-step (BK=32): A tile 16x32 (1KB, staged
// by wave 0) + B tile 512x32 (32KB, 4 calls/wave), double-buffered (66KB).
// Epilogue: v = acc + bias + x kept in fp32 (no bf16 y round-trip);
// per-wave 64-col partial sums via 4-step shfl_xor, cross-wave reduce in
// the dead LDS buffer, then normalize+gamma/beta and write d_out directly.
// Replaces proj_kernel + ln_kernel (one less launch, -16.8MB HBM traffic).
// ---------------------------------------------------------------------------
__global__ __launch_bounds__(512)
void proj_ln_kernel(const __bf16* __restrict__ ctx, const __bf16* __restrict__ Wb,
                    const void* __restrict__ bo, const __bf16* __restrict__ xb,
                    const void* __restrict__ gamma, const void* __restrict__ beta,
                    const int* __restrict__ flag, void* __restrict__ out)
{
    __shared__ __align__(16) char smem[67584];   // 2 x (A 1KB | B 32KB)

    const int isf = *flag;
    const int tid = threadIdx.x;
    const int w = tid >> 6, l = tid & 63;
    const int lane16 = l & 15, quad = l >> 4;
    const int m0 = blockIdx.x * 16;

    const __bf16* Wo = Wb + (size_t)3 * 262144;
    const int cwl = tid;

    // A staging (wave 0 only): slots 0..63, row = s>>2, granule swizzled
    const int gA = (cwl & 3) ^ ((cwl >> 3) & 3);
    const __bf16* aS = ctx + (size_t)(m0 + ((cwl & 63) >> 2)) * D + gA * 8;

    // B staging: slots c*512 + cwl (c = 0..3), row = s>>2 (0..511)
    const __bf16* bS[4];
#pragma unroll
    for (int c = 0; c < 4; ++c) {
        const int s = c * 512 + cwl;
        const int gB = (s & 3) ^ ((s >> 3) & 3);
        bS[c] = Wo + (size_t)(s >> 2) * D + gB * 8;
    }

    const int sw = (quad ^ ((lane16 >> 1) & 3)) * 16;
    const int aoff = lane16 * 64 + sw;                       // A row = lane16
    const int boff = 1024 + (w * 64 + lane16) * 64 + sw;     // B row = col

    f32x4 acc[4];
#pragma unroll
    for (int j = 0; j < 4; ++j) acc[j] = (f32x4){0,0,0,0};

    // prologue: stage kt=0 into buf 0
    if (w == 0) gload_lds16(aS, smem);
#pragma unroll
    for (int c = 0; c < 4; ++c)
        gload_lds16(bS[c], smem + 1024 + c * 8192 + w * 1024);

    for (int kt = 0; kt < D / 32; ++kt) {
        __syncthreads();

        const char* bufp = smem + (kt & 1) * 33792;
        if (kt + 1 < D / 32) {
            char* nb = smem + ((kt + 1) & 1) * 33792;
            if (w == 0) gload_lds16(aS + (kt + 1) * 32, nb);
#pragma unroll
            for (int c = 0; c < 4; ++c)
                gload_lds16(bS[c] + (kt + 1) * 32,
                            nb + 1024 + c * 8192 + w * 1024);
        }

        const bf16x8 af = *(const bf16x8*)(bufp + aoff);
        bf16x8 bf[4];
#pragma unroll
        for (int j = 0; j < 4; ++j) bf[j] = *(const bf16x8*)(bufp + boff + j * 1024);
#pragma unroll
        for (int j = 0; j < 4; ++j)
            acc[j] = mfma16(af, bf[j], acc[j]);
    }

    // ---- epilogue: bias + residual (fp32), then in-block LayerNorm ----
    float bvv[4], gv[4], bev[4];
#pragma unroll
    for (int j = 0; j < 4; ++j) {
        const int col = w * 64 + 16 * j + lane16;
        bvv[j] = ldf(bo, col, isf);
        gv[j]  = ldf(gamma, col, isf);
        bev[j] = ldf(beta, col, isf);
    }

    // v[r][j] = acc + bias + x  (cached in regs; 16 floats)
    float v[4][4];
#pragma unroll
    for (int r = 0; r < 4; ++r) {
        const int tok = m0 + quad * 4 + r;
#pragma unroll
        for (int j = 0; j < 4; ++j) {
            const int col = w * 64 + 16 * j + lane16;
            v[r][j] = acc[j][r] + bvv[j] + (float)xb[(size_t)tok * D + col];
        }
    }

    // per-wave 64-col partials: reduce over lane16 (4-step shfl_xor)
#pragma unroll
    for (int r = 0; r < 4; ++r) {
        float s1 = v[r][0] + v[r][1] + v[r][2] + v[r][3];
        float s2 = v[r][0]*v[r][0] + v[r][1]*v[r][1]
                 + v[r][2]*v[r][2] + v[r][3]*v[r][3];
#pragma unroll
        for (int msk = 1; msk < 16; msk <<= 1) {
            s1 += __shfl_xor(s1, msk);
            s2 += __shfl_xor(s2, msk);
        }
        if (lane16 == 0) {
            // partial[w][row] in dead buf-0 region (last compute used buf 1)
            float* pp = (float*)(smem + ((w * 16 + quad * 4 + r) * 8));
            pp[0] = s1;
            pp[1] = s2;
        }
    }
    __syncthreads();

    // cross-wave reduce: 16 tokens, thread t<16 sums 8 wave-partials
    if (tid < 16) {
        float s1 = 0.f, s2 = 0.f;
#pragma unroll
        for (int ww = 0; ww < 8; ++ww) {
            const float* pp = (const float*)(smem + ((ww * 16 + tid) * 8));
            s1 += pp[0];
            s2 += pp[1];
        }
        const float mean = s1 * (1.0f / D);
        const float var  = s2 * (1.0f / D) - mean * mean;
        float* st = (float*)(smem + 2048 + tid * 8);
        st[0] = mean;
        st[1] = rsqrtf(var + 1e-5f);
    }
    __syncthreads();

    // normalize + write
#pragma unroll
    for (int r = 0; r < 4; ++r) {
        const int row = quad * 4 + r;
        const float* st = (const float*)(smem + 2048 + row * 8);
        const float mean = st[0], rstd = st[1];
        const size_t tb = (size_t)(m0 + row) * D;
#pragma unroll
        for (int j = 0; j < 4; ++j) {
            const int col = w * 64 + 16 * j + lane16;
            const float res = (v[r][j] - mean) * rstd * gv[j] + bev[j];
            if (isf) ((float*)out)[tb + col] = res;
            else     ((__bf16*)out)[tb + col] = (__bf16)res;
        }
    }
}

// ---------------------------------------------------------------------------
extern "C" void kernel_launch(void* const* d_in, const int* in_sizes, int n_in,
                              void* d_out, int out_size, void* d_ws,
                              size_t ws_size, hipStream_t stream)
{
    const void* x     = d_in[0];
    const void* Wq    = d_in[1];
    const void* bq    = d_in[2];
    const void* Wk    = d_in[3];
    const void* bk    = d_in[4];
    const void* Wv    = d_in[5];
    const void* bv    = d_in[6];
    const void* Wo    = d_in[7];
    const void* bo    = d_in[8];
    const void* gamma = d_in[9];
    const void* beta  = d_in[10];

    char* ws = (char*)d_ws;
    __bf16* xb  = (__bf16*)(ws + OFF_XB);
    __bf16* Wb  = (__bf16*)(ws + OFF_WB);
    __bf16* Qb  = (__bf16*)(ws + OFF_Q);
    __bf16* Kb  = (__bf16*)(ws + OFF_K);
    __bf16* Vtb = (__bf16*)(ws + OFF_VT);
    __bf16* ctx = (__bf16*)(ws + OFF_CTX);
    int*    flag = (int*)(ws + OFF_FLAG);

    cvt_kernel<<<5242880 / (256 * 8), 256, 0, stream>>>(
        x, Wq, Wk, Wv, Wo, xb, Wb, flag);
    qkv_kernel<<<dim3(N_TOK / 128, 12), 256, 0, stream>>>(
        xb, Wb, bq, bk, bv, flag, Qb, Kb, Vtb);
    attn_kernel<<<dim3(512), 512, 0, stream>>>(Qb, Kb, Vtb, ctx);
    proj_ln_kernel<<<dim3(N_TOK / 16), 512, 0, stream>>>(
        ctx, Wb, bo, xb, gamma, beta, flag, d_out);
}